// Round 8
// baseline (571.708 us; speedup 1.0000x reference)
//
#include <hip/hip_runtime.h>
#include <hip/hip_bf16.h>

#define N_USERC 50000
#define N_ITEMC 50000
#define NTOT    100000
#define NNZC    3200000
#define NGRP    (NNZC/4)       // 800000 groups of 4 edges
#define EMBC    64
#define BATCHC  4096
#define NSLOT   (3*BATCHC)
#define NBKT    196            // buckets of 512 rows
#define CAP     17408          // fixed bucket capacity: mean 16384 + 8 sigma
#define NSEG2   4              // column segments of 32768 (4.2MB xb slice ~ per-XCD L2)
typedef unsigned long long u64;

typedef __attribute__((ext_vector_type(4))) float floatx4;
typedef __attribute__((ext_vector_type(2))) float floatx2;
typedef __attribute__((ext_vector_type(4))) int   intx4;
typedef __attribute__((ext_vector_type(2))) int   intx2;
typedef __attribute__((ext_vector_type(2))) unsigned uintx2;
typedef __attribute__((ext_vector_type(8))) short shortx8;   // 8 bf16 = 4 VGPRs

__device__ __forceinline__ float bf2f(unsigned short u) {
    return __int_as_float(((int)u) << 16);
}
__device__ __forceinline__ unsigned short f2bf(float f) {
    __hip_bfloat16 h = __float2bfloat16(f);      // RTNE
    return *(unsigned short*)&h;
}
// adj_val in [0,1/32): 15-bit fixed point, step 2^-20 (rel err ~6e-5)
__device__ __forceinline__ unsigned v2fix(float v) {
    int q = (int)(v * 1048576.0f + 0.5f);
    return (unsigned)min(q, 32767);
}

// ---------------- prep: xb0 convert + W^T transpose (6 blocks) + gbcur init (1 block) ----------------
#define NB_INIT  (NTOT * EMBC / 4 / 256)   // 6250
__global__ void k_prep(const float4* __restrict__ ue, const float4* __restrict__ ie,
                       ushort4* __restrict__ xb0,
                       const float* __restrict__ Wgc, const float* __restrict__ Wbi,
                       const float* __restrict__ bgc, const float* __restrict__ bbi,
                       unsigned short* __restrict__ wgT, unsigned short* __restrict__ wbT,
                       float* __restrict__ biasSum, int* __restrict__ gbcur) {
    __shared__ float wlds[64 * 65];
    int tid = threadIdx.x;
    if (blockIdx.x < NB_INIT) {
        long i = (long)blockIdx.x * 256 + tid;
        const long nu4 = (long)N_USERC * EMBC / 4;
        float4 v = (i < nu4) ? ue[i] : ie[i - nu4];
        ushort4 b; b.x = f2bf(v.x); b.y = f2bf(v.y); b.z = f2bf(v.z); b.w = f2bf(v.w);
        xb0[i] = b;
    } else if (blockIdx.x < NB_INIT + 6) {
        int wb = blockIdx.x - NB_INIT;
        int k = wb >> 1, m = wb & 1;
        const float* W = (m ? Wbi : Wgc) + k * 4096;
        unsigned short* WT = (m ? wbT : wgT) + k * 4096;
        #pragma unroll
        for (int it = 0; it < 4; ++it) {
            int i = it * 1024 + tid * 4;          // linear index d*64+c, float4
            float4 v = *(const float4*)(W + i);
            int d = i >> 6, c = i & 63;
            wlds[d * 65 + c + 0] = v.x;
            wlds[d * 65 + c + 1] = v.y;
            wlds[d * 65 + c + 2] = v.z;
            wlds[d * 65 + c + 3] = v.w;
        }
        __syncthreads();
        int c = tid >> 2;
        int d0 = (tid & 3) * 16;
        unsigned short vals[16];
        #pragma unroll
        for (int j = 0; j < 16; ++j)
            vals[j] = f2bf(wlds[(d0 + j) * 65 + c]);
        *(uint4*)(WT + tid * 16)     = *(const uint4*)(vals);
        *(uint4*)(WT + tid * 16 + 8) = *(const uint4*)(vals + 8);
        if (m == 0 && tid < 64) biasSum[k * 64 + tid] = bgc[k * 64 + tid] + bbi[k * 64 + tid];
    } else {
        if (tid < NBKT) gbcur[tid] = tid * CAP;
    }
}

// ---------------- pack + bucket partition in one pass: block-bulk reservation, fixed bases ----------------
__global__ __launch_bounds__(256) void k_scatterP(const intx4* __restrict__ row4, const intx4* __restrict__ col4,
                                                  const floatx4* __restrict__ val4, int* __restrict__ gbcur,
                                                  u64* __restrict__ eb) {
    __shared__ int bh[NBKT], bbase[NBKT], bcur[NBKT];
    int tid = threadIdx.x;
    for (int i = tid; i < NBKT; i += 256) { bh[i] = 0; bcur[i] = 0; }
    __syncthreads();
    long gbase = (long)blockIdx.x * 1024;     // 1024 groups = 4096 edges per block
    u64 e[16]; int bk[16];
    #pragma unroll
    for (int it = 0; it < 4; ++it) {
        long g = gbase + it * 256 + tid;
        if (g < NGRP) {
            intx4 r = __builtin_nontemporal_load(row4 + g);
            intx4 c = __builtin_nontemporal_load(col4 + g);
            floatx4 v = __builtin_nontemporal_load(val4 + g);
            e[it*4+0] = ((u64)r.x << 32) | ((u64)(unsigned)c.x << 15) | v2fix(v.x); bk[it*4+0] = r.x >> 9;
            e[it*4+1] = ((u64)r.y << 32) | ((u64)(unsigned)c.y << 15) | v2fix(v.y); bk[it*4+1] = r.y >> 9;
            e[it*4+2] = ((u64)r.z << 32) | ((u64)(unsigned)c.z << 15) | v2fix(v.z); bk[it*4+2] = r.z >> 9;
            e[it*4+3] = ((u64)r.w << 32) | ((u64)(unsigned)c.w << 15) | v2fix(v.w); bk[it*4+3] = r.w >> 9;
            atomicAdd(&bh[bk[it*4+0]], 1);
            atomicAdd(&bh[bk[it*4+1]], 1);
            atomicAdd(&bh[bk[it*4+2]], 1);
            atomicAdd(&bh[bk[it*4+3]], 1);
        } else {
            bk[it*4+0] = bk[it*4+1] = bk[it*4+2] = bk[it*4+3] = -1;
        }
    }
    __syncthreads();
    for (int i = tid; i < NBKT; i += 256)
        if (bh[i] > 0) bbase[i] = atomicAdd(&gbcur[i], bh[i]);
    __syncthreads();
    #pragma unroll
    for (int i = 0; i < 16; i++) {
        if (bk[i] >= 0) {
            int p = bbase[bk[i]] + atomicAdd(&bcur[bk[i]], 1);
            eb[p] = e[i];
        }
    }
}

// ---------------- bucket -> (row, colseg)-sorted CSR: 2048 bins, rpA (start) + rpC (seg counts) ----------------
__global__ __launch_bounds__(1024) void k_csrC(const u64* __restrict__ eb, const int* __restrict__ gbcur,
                                               int* __restrict__ rpA, ushort4* __restrict__ rpC,
                                               unsigned* __restrict__ ecv) {
    __shared__ int lhist[2048];
    __shared__ int lcur[2048];
    __shared__ int sm[1024];
    int b = blockIdx.x;
    int tid = threadIdx.x;
    int row0 = b << 9;
    lhist[tid] = 0; lhist[tid + 1024] = 0;
    __syncthreads();
    int start = b * CAP;
    int end = gbcur[b];          // final cursor after scatterP
    for (int e = start + tid; e < end; e += 1024) {
        u64 w = eb[e];
        unsigned lo = (unsigned)w;
        int rl = (int)((w >> 32) & 0x1FFFF) - row0;
        int seg = lo >> 30;                        // col>>15 (col = lo>>15, 17 bits)
        atomicAdd(&lhist[(rl << 2) | seg], 1);
    }
    __syncthreads();
    int h0 = lhist[2 * tid], h1 = lhist[2 * tid + 1];
    int pair = h0 + h1;
    sm[tid] = pair;
    __syncthreads();
    for (int off = 1; off < 1024; off <<= 1) {
        int u = (tid >= off) ? sm[tid - off] : 0;
        __syncthreads();
        sm[tid] += u;
        __syncthreads();
    }
    int pairExcl = sm[tid] - pair;
    lcur[2 * tid] = start + pairExcl;
    lcur[2 * tid + 1] = start + pairExcl + h0;
    __syncthreads();
    if (tid < 512) {
        int r = row0 + tid;
        if (r < NTOT) {
            rpA[r] = lcur[4 * tid];
            ushort4 c;
            c.x = (unsigned short)lhist[4 * tid];
            c.y = (unsigned short)lhist[4 * tid + 1];
            c.z = (unsigned short)lhist[4 * tid + 2];
            c.w = (unsigned short)lhist[4 * tid + 3];
            rpC[r] = c;
        }
    }
    __syncthreads();
    for (int e = start + tid; e < end; e += 1024) {
        u64 w = eb[e];
        unsigned lo = (unsigned)w;
        int rl = (int)((w >> 32) & 0x1FFFF) - row0;
        int seg = lo >> 30;
        int p = atomicAdd(&lcur[(rl << 2) | seg], 1);
        ecv[p] = lo;   // col<<15 | val15
    }
}

// ---------------- SpMM v5: segment-phased, persistent, register acc + wave-private LDS spill ----------------
// All 2048 blocks co-resident. Phase s: every wave processes only its rows' seg-s edges ->
// chip-wide gather working set = one 4.2MB xb column slice -> per-XCD L2-resident reuse.
// Partial sums persist across phases in wave-private LDS (reduce-across-q, 16B/row). No atomics.
#define SPMM_BLOCKS 2048
#define RSLOT 13
__global__ __launch_bounds__(256) void k_spmm(const int* __restrict__ rpA, const ushort4* __restrict__ rpC,
                                              const unsigned* __restrict__ ecv,
                                              const unsigned short* __restrict__ xb,
                                              unsigned short* __restrict__ side_bf) {
    __shared__ float accf[4 * RSLOT * 64];   // 13312 B: [wave][rowslot][16 lanes][4 floats]
    int tid = threadIdx.x;
    int wv = tid >> 6, lane = tid & 63, q = lane >> 4, l16 = lane & 15;
    int wid = blockIdx.x * 4 + wv;
    for (int i = tid; i < 4 * RSLOT * 64; i += 256) accf[i] = 0.f;
    __syncthreads();                         // only sync: acc regions are wave-private after this
    float* myacc = accf + wv * RSLOT * 64;
    int t4 = l16 * 4;
    unsigned tb = (unsigned)(t4 * 2);
    const char* xbc = (const char*)xb;
    for (int s = 0; s < NSEG2; ++s) {
        int k = 0;
        for (int r = wid; r < NTOT; r += SPMM_BLOCKS * 4, ++k) {
            int off = rpA[r];
            ushort4 c = rpC[r];
            int cnt;
            if (s == 0)      { cnt = c.x; }
            else if (s == 1) { off += c.x; cnt = c.y; }
            else if (s == 2) { off += c.x + c.y; cnt = c.z; }
            else             { off += c.x + c.y + c.z; cnt = c.w; }
            float* slot = myacc + k * 64 + t4;
            floatx4 prev = *(const floatx4*)slot;    // broadcast read across q groups
            float a0 = (q == 0) ? prev.x : 0.f;
            float a1 = (q == 0) ? prev.y : 0.f;
            float a2 = (q == 0) ? prev.z : 0.f;
            float a3 = (q == 0) ? prev.w : 0.f;
            if (cnt > 0) {
                bool vm = q < cnt;
                unsigned pk = __builtin_nontemporal_load(ecv + (vm ? off + q : off));
                int j = 0;
                while (true) {
                    int jn = j + 4;
                    bool vmn = (jn + q) < cnt;
                    unsigned pkn = __builtin_nontemporal_load(ecv + (vmn ? off + jn + q : off));
                    uintx2 xv = *(const uintx2*)(xbc + ((pk >> 15) * 128u + tb));
                    float w = vm ? (float)(pk & 0x7fffu) : 0.f;
                    a0 += w * __uint_as_float(xv.x << 16);
                    a1 += w * __uint_as_float(xv.x & 0xffff0000u);
                    a2 += w * __uint_as_float(xv.y << 16);
                    a3 += w * __uint_as_float(xv.y & 0xffff0000u);
                    if (jn >= cnt) break;
                    j = jn; pk = pkn; vm = vmn;
                }
            }
            // fold q groups into q==0 lanes
            a0 += __shfl_xor(a0, 16); a1 += __shfl_xor(a1, 16); a2 += __shfl_xor(a2, 16); a3 += __shfl_xor(a3, 16);
            a0 += __shfl_xor(a0, 32); a1 += __shfl_xor(a1, 32); a2 += __shfl_xor(a2, 32); a3 += __shfl_xor(a3, 32);
            if (s < NSEG2 - 1) {
                if (lane < 16) { floatx4 v = {a0, a1, a2, a3}; *(floatx4*)slot = v; }
            } else {
                if (lane < 16) {
                    const float SC = 1.0f / 1048576.0f;    // deferred fixed-point scale
                    ushort4 o; o.x = f2bf(a0 * SC); o.y = f2bf(a1 * SC); o.z = f2bf(a2 * SC); o.w = f2bf(a3 * SC);
                    *(ushort4*)(side_bf + (long)r * EMBC + t4) = o;
                }
            }
        }
    }
}

// ------------- MFMA layer: xb_in -> xb_out -------------
#define RPB 128
#define LDP 72
__global__ __launch_bounds__(256) void k_layer_mfma(
    const unsigned short* __restrict__ side_bf, const unsigned short* __restrict__ xb_in,
    unsigned short* __restrict__ xb_out,
    const unsigned short* __restrict__ wgT, const unsigned short* __restrict__ wbT,
    const float* __restrict__ biasSum)
{
    __shared__ unsigned short sS[RPB * LDP];
    __shared__ unsigned short sM[RPB * LDP];
    __shared__ unsigned short sWg[64 * LDP];
    __shared__ unsigned short sWb[64 * LDP];
    __shared__ float sBias[64];

    int tid = threadIdx.x;
    int row0 = blockIdx.x * RPB;

    #pragma unroll
    for (int it = 0; it < 2; ++it) {
        int item = it * 256 + tid;          // 0..511
        int c = item >> 3, ch = item & 7;
        *(uint4*)(sWg + c * LDP + ch * 8) = *(const uint4*)(wgT + c * 64 + ch * 8);
        *(uint4*)(sWb + c * LDP + ch * 8) = *(const uint4*)(wbT + c * 64 + ch * 8);
    }
    if (tid < 64) sBias[tid] = biasSum[tid];

    #pragma unroll
    for (int it = 0; it < (RPB * 8) / 256; ++it) {
        int item = it * 256 + tid;
        int r = item >> 3, ch = item & 7;
        long grow = row0 + r;
        uint4 sv = make_uint4(0, 0, 0, 0), ev = make_uint4(0, 0, 0, 0);
        if (grow < NTOT) {
            sv = *(const uint4*)(side_bf + grow * 64 + ch * 8);
            ev = *(const uint4*)(xb_in + grow * 64 + ch * 8);
        }
        uint4 mv;
        mv.x = f2bf(bf2f(ev.x & 0xffff) * bf2f(sv.x & 0xffff)) |
               ((unsigned int)f2bf(bf2f(ev.x >> 16) * bf2f(sv.x >> 16)) << 16);
        mv.y = f2bf(bf2f(ev.y & 0xffff) * bf2f(sv.y & 0xffff)) |
               ((unsigned int)f2bf(bf2f(ev.y >> 16) * bf2f(sv.y >> 16)) << 16);
        mv.z = f2bf(bf2f(ev.z & 0xffff) * bf2f(sv.z & 0xffff)) |
               ((unsigned int)f2bf(bf2f(ev.z >> 16) * bf2f(sv.z >> 16)) << 16);
        mv.w = f2bf(bf2f(ev.w & 0xffff) * bf2f(sv.w & 0xffff)) |
               ((unsigned int)f2bf(bf2f(ev.w >> 16) * bf2f(sv.w >> 16)) << 16);
        *(uint4*)(sS + r * LDP + ch * 8) = sv;
        *(uint4*)(sM + r * LDP + ch * 8) = mv;
    }
    __syncthreads();

    int wave = tid >> 6, lane = tid & 63;
    int quad = lane >> 4, l16 = lane & 15;

    floatx4 accG[2][4], accB[2][4];
    #pragma unroll
    for (int rt = 0; rt < 2; rt++)
        #pragma unroll
        for (int ct = 0; ct < 4; ct++) {
            accG[rt][ct] = (floatx4){0.f, 0.f, 0.f, 0.f};
            accB[rt][ct] = (floatx4){0.f, 0.f, 0.f, 0.f};
        }

    #pragma unroll
    for (int kc = 0; kc < 64; kc += 32) {
        shortx8 aS[2], aM[2];
        #pragma unroll
        for (int rt = 0; rt < 2; rt++) {
            int r = wave * 32 + rt * 16 + l16;
            aS[rt] = *(const shortx8*)(sS + r * LDP + kc + quad * 8);
            aM[rt] = *(const shortx8*)(sM + r * LDP + kc + quad * 8);
        }
        #pragma unroll
        for (int ct = 0; ct < 4; ct++) {
            int c = ct * 16 + l16;
            shortx8 bG = *(const shortx8*)(sWg + c * LDP + kc + quad * 8);
            shortx8 bB = *(const shortx8*)(sWb + c * LDP + kc + quad * 8);
            #pragma unroll
            for (int rt = 0; rt < 2; rt++) {
                accG[rt][ct] = __builtin_amdgcn_mfma_f32_16x16x32_bf16(aS[rt], bG, accG[rt][ct], 0, 0, 0);
                accB[rt][ct] = __builtin_amdgcn_mfma_f32_16x16x32_bf16(aM[rt], bB, accB[rt][ct], 0, 0, 0);
            }
        }
    }

    #pragma unroll
    for (int rt = 0; rt < 2; rt++)
        #pragma unroll
        for (int ct = 0; ct < 4; ct++) {
            int c = ct * 16 + l16;
            float bs = sBias[c];
            #pragma unroll
            for (int reg = 0; reg < 4; reg++) {
                int r = wave * 32 + rt * 16 + quad * 4 + reg;
                long grow = row0 + r;
                if (grow < NTOT) {
                    float v = accG[rt][ct][reg] + accB[rt][ct][reg] + bs;
                    float o = (v > 0.f) ? v : 0.2f * v;
                    xb_out[grow * 64 + c] = f2bf(o);
                }
            }
        }
}

// ------------- single fused gather: all 4 column-blocks (layer 0 raw, 1-3 normalized) -------------
__global__ __launch_bounds__(256) void k_gatherAll(
    const unsigned short* __restrict__ xb0, const unsigned short* __restrict__ xb1,
    const unsigned short* __restrict__ xb2, const unsigned short* __restrict__ xb3,
    const int* __restrict__ users, const int* __restrict__ pos, const int* __restrict__ neg,
    float* __restrict__ out) {
    int gw = (blockIdx.x * blockDim.x + threadIdx.x) >> 6;   // slot*4 + layer
    int lane = threadIdx.x & 63;
    int slot = gw >> 2, layer = gw & 3;
    if (slot >= NSLOT) return;
    int row;
    if (slot < BATCHC)          row = users[slot];
    else if (slot < 2 * BATCHC) row = N_USERC + pos[slot - BATCHC];
    else                        row = N_USERC + neg[slot - 2 * BATCHC];
    const unsigned short* src = (layer == 0) ? xb0 : (layer == 1) ? xb1 : (layer == 2) ? xb2 : xb3;
    float v = bf2f(src[(long)row * 64 + lane]);
    if (layer != 0) {
        float ss = v * v;
        for (int off = 32; off > 0; off >>= 1) ss += __shfl_xor(ss, off);
        float nrm = fmaxf(sqrtf(ss), 1e-12f);
        v = v / nrm;
    }
    out[(long)slot * 256 + layer * 64 + lane] = v;
}

extern "C" void kernel_launch(void* const* d_in, const int* in_sizes, int n_in,
                              void* d_out, int out_size, void* d_ws, size_t ws_size,
                              hipStream_t stream) {
    const int*   users   = (const int*)d_in[0];
    const int*   pos     = (const int*)d_in[1];
    const int*   neg     = (const int*)d_in[2];
    const int*   adj_row = (const int*)d_in[3];
    const int*   adj_col = (const int*)d_in[4];
    const float* adj_val = (const float*)d_in[5];
    const float* user_emb = (const float*)d_in[6];
    const float* item_emb = (const float*)d_in[7];
    const float* W_gc = (const float*)d_in[8];
    const float* b_gc = (const float*)d_in[9];
    const float* W_bi = (const float*)d_in[10];
    const float* b_bi = (const float*)d_in[11];
    float* out = (float*)d_out;

    // workspace (~82 MB). Aliasing: xb2/xb3 overlay eb (eb dead after csrC).
    char* p = (char*)d_ws;
    unsigned* ecv = (unsigned*)p;               p += (size_t)NBKT * CAP * 4;   // 13.65 MB (gapped CSR edges)
    u64*  eb  = (u64*)p;                        p += (size_t)NBKT * CAP * 8;   // 27.3 MB
    unsigned short* xb2 = (unsigned short*)eb;
    unsigned short* xb3 = (unsigned short*)((char*)eb + (size_t)NTOT * EMBC * 2);
    unsigned short* side_bf = (unsigned short*)p; p += (size_t)NTOT * EMBC * 2;
    unsigned short* xb0 = (unsigned short*)p;   p += (size_t)NTOT * EMBC * 2;
    unsigned short* xb1 = (unsigned short*)p;   p += (size_t)NTOT * EMBC * 2;
    int*  rpA = (int*)p;                        p += (size_t)NTOT * 4 + 64;
    ushort4* rpC = (ushort4*)p;                 p += (size_t)NTOT * 8 + 64;
    int*  gbcur = (int*)p;                      p += 1024;
    unsigned short* wgT = (unsigned short*)p;   p += 3 * 4096 * 2;
    unsigned short* wbT = (unsigned short*)p;   p += 3 * 4096 * 2;
    float* biasSum = (float*)p;                 p += 3 * 64 * 4;

    k_prep<<<NB_INIT + 7, 256, 0, stream>>>(
        (const float4*)user_emb, (const float4*)item_emb, (ushort4*)xb0,
        W_gc, W_bi, b_gc, b_bi, wgT, wbT, biasSum, gbcur);

    k_scatterP<<<(NNZC + 4095) / 4096, 256, 0, stream>>>(
        (const intx4*)adj_row, (const intx4*)adj_col, (const floatx4*)adj_val, gbcur, eb);
    k_csrC<<<NBKT, 1024, 0, stream>>>(eb, gbcur, rpA, rpC, ecv);

    unsigned short* xbs[4] = {xb0, xb1, xb2, xb3};
    const int NB_LAYER = (NTOT + RPB - 1) / RPB;
    for (int k = 0; k < 3; k++) {
        k_spmm<<<SPMM_BLOCKS, 256, 0, stream>>>(rpA, rpC, ecv, xbs[k], side_bf);
        k_layer_mfma<<<NB_LAYER, 256, 0, stream>>>(side_bf, xbs[k], xbs[k + 1],
            wgT + (size_t)k * 4096, wbT + (size_t)k * 4096, biasSum + (size_t)k * 64);
    }
    k_gatherAll<<<(NSLOT * 4) / 4, 256, 0, stream>>>(xb0, xb1, xb2, xb3, users, pos, neg, out);
}

// Round 9
// 457.420 us; speedup vs baseline: 1.2499x; 1.2499x over previous
//
#include <hip/hip_runtime.h>
#include <hip/hip_bf16.h>

#define N_USERC 50000
#define N_ITEMC 50000
#define NTOT    100000
#define NNZC    3200000
#define NGRP    (NNZC/4)       // 800000 groups of 4 edges
#define EMBC    64
#define BATCHC  4096
#define NSLOT   (3*BATCHC)
#define NBKT    196            // buckets of 512 rows
#define CAP     17408          // fixed bucket capacity: mean 16384 + 8 sigma
typedef unsigned long long u64;

typedef __attribute__((ext_vector_type(4))) float floatx4;
typedef __attribute__((ext_vector_type(2))) float floatx2;
typedef __attribute__((ext_vector_type(4))) int   intx4;
typedef __attribute__((ext_vector_type(2))) int   intx2;
typedef __attribute__((ext_vector_type(2))) unsigned uintx2;
typedef __attribute__((ext_vector_type(8))) short shortx8;   // 8 bf16 = 4 VGPRs

__device__ __forceinline__ float bf2f(unsigned short u) {
    return __int_as_float(((int)u) << 16);
}
__device__ __forceinline__ unsigned short f2bf(float f) {
    __hip_bfloat16 h = __float2bfloat16(f);      // RTNE
    return *(unsigned short*)&h;
}
// adj_val in [0,1/32): 15-bit fixed point, step 2^-20 (rel err ~6e-5)
__device__ __forceinline__ unsigned v2fix(float v) {
    int q = (int)(v * 1048576.0f + 0.5f);
    return (unsigned)min(q, 32767);
}

// ---------------- prep: xb0 convert + W^T transpose (6 blocks) + gbcur init (1 block) ----------------
#define NB_INIT  (NTOT * EMBC / 4 / 256)   // 6250
__global__ void k_prep(const float4* __restrict__ ue, const float4* __restrict__ ie,
                       ushort4* __restrict__ xb0,
                       const float* __restrict__ Wgc, const float* __restrict__ Wbi,
                       const float* __restrict__ bgc, const float* __restrict__ bbi,
                       unsigned short* __restrict__ wgT, unsigned short* __restrict__ wbT,
                       float* __restrict__ biasSum, int* __restrict__ gbcur) {
    __shared__ float wlds[64 * 65];
    int tid = threadIdx.x;
    if (blockIdx.x < NB_INIT) {
        long i = (long)blockIdx.x * 256 + tid;
        const long nu4 = (long)N_USERC * EMBC / 4;
        float4 v = (i < nu4) ? ue[i] : ie[i - nu4];
        ushort4 b; b.x = f2bf(v.x); b.y = f2bf(v.y); b.z = f2bf(v.z); b.w = f2bf(v.w);
        xb0[i] = b;
    } else if (blockIdx.x < NB_INIT + 6) {
        int wb = blockIdx.x - NB_INIT;
        int k = wb >> 1, m = wb & 1;
        const float* W = (m ? Wbi : Wgc) + k * 4096;
        unsigned short* WT = (m ? wbT : wgT) + k * 4096;
        #pragma unroll
        for (int it = 0; it < 4; ++it) {
            int i = it * 1024 + tid * 4;          // linear index d*64+c, float4
            float4 v = *(const float4*)(W + i);
            int d = i >> 6, c = i & 63;
            wlds[d * 65 + c + 0] = v.x;
            wlds[d * 65 + c + 1] = v.y;
            wlds[d * 65 + c + 2] = v.z;
            wlds[d * 65 + c + 3] = v.w;
        }
        __syncthreads();
        int c = tid >> 2;
        int d0 = (tid & 3) * 16;
        unsigned short vals[16];
        #pragma unroll
        for (int j = 0; j < 16; ++j)
            vals[j] = f2bf(wlds[(d0 + j) * 65 + c]);
        *(uint4*)(WT + tid * 16)     = *(const uint4*)(vals);
        *(uint4*)(WT + tid * 16 + 8) = *(const uint4*)(vals + 8);
        if (m == 0 && tid < 64) biasSum[k * 64 + tid] = bgc[k * 64 + tid] + bbi[k * 64 + tid];
    } else {
        if (tid < NBKT) gbcur[tid] = tid * CAP;
    }
}

// ---------------- pack + bucket partition in one pass: block-bulk reservation, fixed bases ----------------
__global__ __launch_bounds__(256) void k_scatterP(const intx4* __restrict__ row4, const intx4* __restrict__ col4,
                                                  const floatx4* __restrict__ val4, int* __restrict__ gbcur,
                                                  u64* __restrict__ eb) {
    __shared__ int bh[NBKT], bbase[NBKT], bcur[NBKT];
    int tid = threadIdx.x;
    for (int i = tid; i < NBKT; i += 256) { bh[i] = 0; bcur[i] = 0; }
    __syncthreads();
    long gbase = (long)blockIdx.x * 1024;     // 1024 groups = 4096 edges per block
    u64 e[16]; int bk[16];
    #pragma unroll
    for (int it = 0; it < 4; ++it) {
        long g = gbase + it * 256 + tid;
        if (g < NGRP) {
            intx4 r = __builtin_nontemporal_load(row4 + g);
            intx4 c = __builtin_nontemporal_load(col4 + g);
            floatx4 v = __builtin_nontemporal_load(val4 + g);
            e[it*4+0] = ((u64)r.x << 32) | ((u64)(unsigned)c.x << 15) | v2fix(v.x); bk[it*4+0] = r.x >> 9;
            e[it*4+1] = ((u64)r.y << 32) | ((u64)(unsigned)c.y << 15) | v2fix(v.y); bk[it*4+1] = r.y >> 9;
            e[it*4+2] = ((u64)r.z << 32) | ((u64)(unsigned)c.z << 15) | v2fix(v.z); bk[it*4+2] = r.z >> 9;
            e[it*4+3] = ((u64)r.w << 32) | ((u64)(unsigned)c.w << 15) | v2fix(v.w); bk[it*4+3] = r.w >> 9;
            atomicAdd(&bh[bk[it*4+0]], 1);
            atomicAdd(&bh[bk[it*4+1]], 1);
            atomicAdd(&bh[bk[it*4+2]], 1);
            atomicAdd(&bh[bk[it*4+3]], 1);
        } else {
            bk[it*4+0] = bk[it*4+1] = bk[it*4+2] = bk[it*4+3] = -1;
        }
    }
    __syncthreads();
    for (int i = tid; i < NBKT; i += 256)
        if (bh[i] > 0) bbase[i] = atomicAdd(&gbcur[i], bh[i]);
    __syncthreads();
    #pragma unroll
    for (int i = 0; i < 16; i++) {
        if (bk[i] >= 0) {
            int p = bbase[bk[i]] + atomicAdd(&bcur[bk[i]], 1);
            eb[p] = e[i];
        }
    }
}

// ---------------- bucket -> (row, colseg)-sorted CSR: 2048 bins, rpA (start) + rpC (seg counts) ----------------
__global__ __launch_bounds__(1024) void k_csrC(const u64* __restrict__ eb, const int* __restrict__ gbcur,
                                               int* __restrict__ rpA, ushort4* __restrict__ rpC,
                                               unsigned* __restrict__ ecv) {
    __shared__ int lhist[2048];
    __shared__ int lcur[2048];
    __shared__ int sm[1024];
    int b = blockIdx.x;
    int tid = threadIdx.x;
    int row0 = b << 9;
    lhist[tid] = 0; lhist[tid + 1024] = 0;
    __syncthreads();
    int start = b * CAP;
    int end = gbcur[b];          // final cursor after scatterP
    for (int e = start + tid; e < end; e += 1024) {
        u64 w = eb[e];
        unsigned lo = (unsigned)w;
        int rl = (int)((w >> 32) & 0x1FFFF) - row0;
        int seg = lo >> 30;                        // col>>15 (col = lo>>15, 17 bits)
        atomicAdd(&lhist[(rl << 2) | seg], 1);
    }
    __syncthreads();
    int h0 = lhist[2 * tid], h1 = lhist[2 * tid + 1];
    int pair = h0 + h1;
    sm[tid] = pair;
    __syncthreads();
    for (int off = 1; off < 1024; off <<= 1) {
        int u = (tid >= off) ? sm[tid - off] : 0;
        __syncthreads();
        sm[tid] += u;
        __syncthreads();
    }
    int pairExcl = sm[tid] - pair;
    lcur[2 * tid] = start + pairExcl;
    lcur[2 * tid + 1] = start + pairExcl + h0;
    __syncthreads();
    if (tid < 512) {
        int r = row0 + tid;
        if (r < NTOT) {
            rpA[r] = lcur[4 * tid];
            ushort4 c;
            c.x = (unsigned short)lhist[4 * tid];
            c.y = (unsigned short)lhist[4 * tid + 1];
            c.z = (unsigned short)lhist[4 * tid + 2];
            c.w = (unsigned short)lhist[4 * tid + 3];
            rpC[r] = c;
        }
    }
    __syncthreads();
    for (int e = start + tid; e < end; e += 1024) {
        u64 w = eb[e];
        unsigned lo = (unsigned)w;
        int rl = (int)((w >> 32) & 0x1FFFF) - row0;
        int seg = lo >> 30;
        int p = atomicAdd(&lcur[(rl << 2) | seg], 1);
        ecv[p] = lo;   // col<<15 | val15
    }
}

// ---------------- SpMM v6: segment-phased + round-7 MLP shape ----------------
// q-group (16 lanes) owns ONE row; wave = 4 rows concurrently; rows r = qg + 32768*k.
// Inner: 4 edges/iter, 4 pk loads + 4 independent gathers (8 vmem in flight/wave = round-7 profile)
// over phase-local contiguous (row,seg) runs. Acc persists across phases in wave-private LDS
// (one 16B ds_read/ds_write per row-phase). No shfl reduce, no atomics, no inter-phase barrier.
#define SPMM_BLOCKS 2048
#define QSLOT 4            // rows per q-group: ceil(100000/32768)
#define SLOTF 68           // floats per row slot (64 + pad; keeps 16B alignment)
__global__ __launch_bounds__(256) void k_spmm(const int* __restrict__ rpA, const ushort4* __restrict__ rpC,
                                              const unsigned* __restrict__ ecv,
                                              const unsigned short* __restrict__ xb,
                                              unsigned short* __restrict__ side_bf) {
    __shared__ float accf[16 * QSLOT * SLOTF];   // [wave*4+q][k] : 17408 B
    int tid = threadIdx.x;
    int wv = tid >> 6, lane = tid & 63, q = lane >> 4, l16 = lane & 15;
    int qg = (blockIdx.x * 4 + wv) * 4 + q;      // global q-group id, 0..32767
    float* myacc = accf + (wv * 4 + q) * QSLOT * SLOTF;
    int t4 = l16 * 4;
    unsigned tb = (unsigned)(t4 * 2);
    const char* xbc = (const char*)xb;
    #pragma unroll
    for (int s = 0; s < 4; ++s) {
        #pragma unroll
        for (int k = 0; k < QSLOT; ++k) {
            int r = qg + 32768 * k;
            if (r < NTOT) {
                int off = rpA[r];
                ushort4 c = rpC[r];
                int cnt;
                if (s == 0)      { cnt = c.x; }
                else if (s == 1) { off += c.x; cnt = c.y; }
                else if (s == 2) { off += c.x + c.y; cnt = c.z; }
                else             { off += c.x + c.y + c.z; cnt = c.w; }
                float* slot = myacc + k * SLOTF + t4;
                floatx2 acc01, acc23;
                if (s == 0) {
                    acc01 = (floatx2){0.f, 0.f}; acc23 = (floatx2){0.f, 0.f};
                } else {
                    floatx4 pv = *(const floatx4*)slot;
                    acc01 = (floatx2){pv.x, pv.y}; acc23 = (floatx2){pv.z, pv.w};
                }
                for (int j = 0; j < cnt; j += 4) {
                    unsigned pk[4];
                    #pragma unroll
                    for (int u = 0; u < 4; ++u) {
                        unsigned pv = __builtin_nontemporal_load(ecv + off + j + u);
                        pk[u] = (j + u < cnt) ? pv : 0u;    // masked: col 0, w 0 (safe gather)
                    }
                    uintx2 xv[4];
                    #pragma unroll
                    for (int u = 0; u < 4; ++u)
                        xv[u] = *(const uintx2*)(xbc + ((pk[u] >> 15) * 128u + tb));
                    #pragma unroll
                    for (int u = 0; u < 4; ++u) {
                        float w = (float)(pk[u] & 0x7fffu);
                        floatx2 x01, x23;
                        x01.x = __uint_as_float(xv[u].x << 16);
                        x01.y = __uint_as_float(xv[u].x & 0xffff0000u);
                        x23.x = __uint_as_float(xv[u].y << 16);
                        x23.y = __uint_as_float(xv[u].y & 0xffff0000u);
                        acc01 += w * x01;
                        acc23 += w * x23;
                    }
                }
                if (s < 3) {
                    floatx4 sv = {acc01.x, acc01.y, acc23.x, acc23.y};
                    *(floatx4*)slot = sv;
                } else {
                    const float SC = 1.0f / 1048576.0f;    // deferred fixed-point scale
                    ushort4 o;
                    o.x = f2bf(acc01.x * SC); o.y = f2bf(acc01.y * SC);
                    o.z = f2bf(acc23.x * SC); o.w = f2bf(acc23.y * SC);
                    *(ushort4*)(side_bf + (long)r * EMBC + t4) = o;
                }
            }
        }
    }
}

// ------------- MFMA layer: xb_in -> xb_out -------------
#define RPB 128
#define LDP 72
__global__ __launch_bounds__(256) void k_layer_mfma(
    const unsigned short* __restrict__ side_bf, const unsigned short* __restrict__ xb_in,
    unsigned short* __restrict__ xb_out,
    const unsigned short* __restrict__ wgT, const unsigned short* __restrict__ wbT,
    const float* __restrict__ biasSum)
{
    __shared__ unsigned short sS[RPB * LDP];
    __shared__ unsigned short sM[RPB * LDP];
    __shared__ unsigned short sWg[64 * LDP];
    __shared__ unsigned short sWb[64 * LDP];
    __shared__ float sBias[64];

    int tid = threadIdx.x;
    int row0 = blockIdx.x * RPB;

    #pragma unroll
    for (int it = 0; it < 2; ++it) {
        int item = it * 256 + tid;          // 0..511
        int c = item >> 3, ch = item & 7;
        *(uint4*)(sWg + c * LDP + ch * 8) = *(const uint4*)(wgT + c * 64 + ch * 8);
        *(uint4*)(sWb + c * LDP + ch * 8) = *(const uint4*)(wbT + c * 64 + ch * 8);
    }
    if (tid < 64) sBias[tid] = biasSum[tid];

    #pragma unroll
    for (int it = 0; it < (RPB * 8) / 256; ++it) {
        int item = it * 256 + tid;
        int r = item >> 3, ch = item & 7;
        long grow = row0 + r;
        uint4 sv = make_uint4(0, 0, 0, 0), ev = make_uint4(0, 0, 0, 0);
        if (grow < NTOT) {
            sv = *(const uint4*)(side_bf + grow * 64 + ch * 8);
            ev = *(const uint4*)(xb_in + grow * 64 + ch * 8);
        }
        uint4 mv;
        mv.x = f2bf(bf2f(ev.x & 0xffff) * bf2f(sv.x & 0xffff)) |
               ((unsigned int)f2bf(bf2f(ev.x >> 16) * bf2f(sv.x >> 16)) << 16);
        mv.y = f2bf(bf2f(ev.y & 0xffff) * bf2f(sv.y & 0xffff)) |
               ((unsigned int)f2bf(bf2f(ev.y >> 16) * bf2f(sv.y >> 16)) << 16);
        mv.z = f2bf(bf2f(ev.z & 0xffff) * bf2f(sv.z & 0xffff)) |
               ((unsigned int)f2bf(bf2f(ev.z >> 16) * bf2f(sv.z >> 16)) << 16);
        mv.w = f2bf(bf2f(ev.w & 0xffff) * bf2f(sv.w & 0xffff)) |
               ((unsigned int)f2bf(bf2f(ev.w >> 16) * bf2f(sv.w >> 16)) << 16);
        *(uint4*)(sS + r * LDP + ch * 8) = sv;
        *(uint4*)(sM + r * LDP + ch * 8) = mv;
    }
    __syncthreads();

    int wave = tid >> 6, lane = tid & 63;
    int quad = lane >> 4, l16 = lane & 15;

    floatx4 accG[2][4], accB[2][4];
    #pragma unroll
    for (int rt = 0; rt < 2; rt++)
        #pragma unroll
        for (int ct = 0; ct < 4; ct++) {
            accG[rt][ct] = (floatx4){0.f, 0.f, 0.f, 0.f};
            accB[rt][ct] = (floatx4){0.f, 0.f, 0.f, 0.f};
        }

    #pragma unroll
    for (int kc = 0; kc < 64; kc += 32) {
        shortx8 aS[2], aM[2];
        #pragma unroll
        for (int rt = 0; rt < 2; rt++) {
            int r = wave * 32 + rt * 16 + l16;
            aS[rt] = *(const shortx8*)(sS + r * LDP + kc + quad * 8);
            aM[rt] = *(const shortx8*)(sM + r * LDP + kc + quad * 8);
        }
        #pragma unroll
        for (int ct = 0; ct < 4; ct++) {
            int c = ct * 16 + l16;
            shortx8 bG = *(const shortx8*)(sWg + c * LDP + kc + quad * 8);
            shortx8 bB = *(const shortx8*)(sWb + c * LDP + kc + quad * 8);
            #pragma unroll
            for (int rt = 0; rt < 2; rt++) {
                accG[rt][ct] = __builtin_amdgcn_mfma_f32_16x16x32_bf16(aS[rt], bG, accG[rt][ct], 0, 0, 0);
                accB[rt][ct] = __builtin_amdgcn_mfma_f32_16x16x32_bf16(aM[rt], bB, accB[rt][ct], 0, 0, 0);
            }
        }
    }

    #pragma unroll
    for (int rt = 0; rt < 2; rt++)
        #pragma unroll
        for (int ct = 0; ct < 4; ct++) {
            int c = ct * 16 + l16;
            float bs = sBias[c];
            #pragma unroll
            for (int reg = 0; reg < 4; reg++) {
                int r = wave * 32 + rt * 16 + quad * 4 + reg;
                long grow = row0 + r;
                if (grow < NTOT) {
                    float v = accG[rt][ct][reg] + accB[rt][ct][reg] + bs;
                    float o = (v > 0.f) ? v : 0.2f * v;
                    xb_out[grow * 64 + c] = f2bf(o);
                }
            }
        }
}

// ------------- single fused gather: all 4 column-blocks (layer 0 raw, 1-3 normalized) -------------
__global__ __launch_bounds__(256) void k_gatherAll(
    const unsigned short* __restrict__ xb0, const unsigned short* __restrict__ xb1,
    const unsigned short* __restrict__ xb2, const unsigned short* __restrict__ xb3,
    const int* __restrict__ users, const int* __restrict__ pos, const int* __restrict__ neg,
    float* __restrict__ out) {
    int gw = (blockIdx.x * blockDim.x + threadIdx.x) >> 6;   // slot*4 + layer
    int lane = threadIdx.x & 63;
    int slot = gw >> 2, layer = gw & 3;
    if (slot >= NSLOT) return;
    int row;
    if (slot < BATCHC)          row = users[slot];
    else if (slot < 2 * BATCHC) row = N_USERC + pos[slot - BATCHC];
    else                        row = N_USERC + neg[slot - 2 * BATCHC];
    const unsigned short* src = (layer == 0) ? xb0 : (layer == 1) ? xb1 : (layer == 2) ? xb2 : xb3;
    float v = bf2f(src[(long)row * 64 + lane]);
    if (layer != 0) {
        float ss = v * v;
        for (int off = 32; off > 0; off >>= 1) ss += __shfl_xor(ss, off);
        float nrm = fmaxf(sqrtf(ss), 1e-12f);
        v = v / nrm;
    }
    out[(long)slot * 256 + layer * 64 + lane] = v;
}

extern "C" void kernel_launch(void* const* d_in, const int* in_sizes, int n_in,
                              void* d_out, int out_size, void* d_ws, size_t ws_size,
                              hipStream_t stream) {
    const int*   users   = (const int*)d_in[0];
    const int*   pos     = (const int*)d_in[1];
    const int*   neg     = (const int*)d_in[2];
    const int*   adj_row = (const int*)d_in[3];
    const int*   adj_col = (const int*)d_in[4];
    const float* adj_val = (const float*)d_in[5];
    const float* user_emb = (const float*)d_in[6];
    const float* item_emb = (const float*)d_in[7];
    const float* W_gc = (const float*)d_in[8];
    const float* b_gc = (const float*)d_in[9];
    const float* W_bi = (const float*)d_in[10];
    const float* b_bi = (const float*)d_in[11];
    float* out = (float*)d_out;

    // workspace (~82 MB). Aliasing: xb2/xb3 overlay eb (eb dead after csrC).
    char* p = (char*)d_ws;
    unsigned* ecv = (unsigned*)p;               p += (size_t)NBKT * CAP * 4;   // 13.65 MB (gapped CSR edges)
    u64*  eb  = (u64*)p;                        p += (size_t)NBKT * CAP * 8;   // 27.3 MB
    unsigned short* xb2 = (unsigned short*)eb;
    unsigned short* xb3 = (unsigned short*)((char*)eb + (size_t)NTOT * EMBC * 2);
    unsigned short* side_bf = (unsigned short*)p; p += (size_t)NTOT * EMBC * 2;
    unsigned short* xb0 = (unsigned short*)p;   p += (size_t)NTOT * EMBC * 2;
    unsigned short* xb1 = (unsigned short*)p;   p += (size_t)NTOT * EMBC * 2;
    int*  rpA = (int*)p;                        p += (size_t)NTOT * 4 + 64;
    ushort4* rpC = (ushort4*)p;                 p += (size_t)NTOT * 8 + 64;
    int*  gbcur = (int*)p;                      p += 1024;
    unsigned short* wgT = (unsigned short*)p;   p += 3 * 4096 * 2;
    unsigned short* wbT = (unsigned short*)p;   p += 3 * 4096 * 2;
    float* biasSum = (float*)p;                 p += 3 * 64 * 4;

    k_prep<<<NB_INIT + 7, 256, 0, stream>>>(
        (const float4*)user_emb, (const float4*)item_emb, (ushort4*)xb0,
        W_gc, W_bi, b_gc, b_bi, wgT, wbT, biasSum, gbcur);

    k_scatterP<<<(NNZC + 4095) / 4096, 256, 0, stream>>>(
        (const intx4*)adj_row, (const intx4*)adj_col, (const floatx4*)adj_val, gbcur, eb);
    k_csrC<<<NBKT, 1024, 0, stream>>>(eb, gbcur, rpA, rpC, ecv);

    unsigned short* xbs[4] = {xb0, xb1, xb2, xb3};
    const int NB_LAYER = (NTOT + RPB - 1) / RPB;
    for (int k = 0; k < 3; k++) {
        k_spmm<<<SPMM_BLOCKS, 256, 0, stream>>>(rpA, rpC, ecv, xbs[k], side_bf);
        k_layer_mfma<<<NB_LAYER, 256, 0, stream>>>(side_bf, xbs[k], xbs[k + 1],
            wgT + (size_t)k * 4096, wbT + (size_t)k * 4096, biasSum + (size_t)k * 64);
    }
    k_gatherAll<<<(NSLOT * 4) / 4, 256, 0, stream>>>(xb0, xb1, xb2, xb3, users, pos, neg, out);
}

// Round 10
// 393.963 us; speedup vs baseline: 1.4512x; 1.1611x over previous
//
#include <hip/hip_runtime.h>
#include <hip/hip_bf16.h>

#define N_USERC 50000
#define N_ITEMC 50000
#define NTOT    100000
#define NNZC    3200000
#define NGRP    (NNZC/4)       // 800000 groups of 4 edges
#define EMBC    64
#define BATCHC  4096
#define NSLOT   (3*BATCHC)
#define NBKT    196            // buckets of 512 rows
#define CAP     17408          // fixed bucket capacity: mean 16384 + 8 sigma
typedef unsigned long long u64;

typedef __attribute__((ext_vector_type(4))) float floatx4;
typedef __attribute__((ext_vector_type(2))) float floatx2;
typedef __attribute__((ext_vector_type(4))) int   intx4;
typedef __attribute__((ext_vector_type(2))) int   intx2;
typedef __attribute__((ext_vector_type(2))) unsigned uintx2;
typedef __attribute__((ext_vector_type(8))) short shortx8;   // 8 bf16 = 4 VGPRs

__device__ __forceinline__ float bf2f(unsigned short u) {
    return __int_as_float(((int)u) << 16);
}
__device__ __forceinline__ unsigned short f2bf(float f) {
    __hip_bfloat16 h = __float2bfloat16(f);      // RTNE
    return *(unsigned short*)&h;
}
// adj_val in [0,1/32): 15-bit fixed point, step 2^-20 (rel err ~6e-5)
__device__ __forceinline__ unsigned v2fix(float v) {
    int q = (int)(v * 1048576.0f + 0.5f);
    return (unsigned)min(q, 32767);
}

// ---------------- fused prep+scatter: one dispatch ----------------
// blocks [0, NB_SCAT): edge pack + bucket scatter (RELATIVE gbcur, zeroed by memset -> no init dep)
// blocks [NB_SCAT, NB_SCAT+NB_INIT): xb0 = bf16(ego)
// blocks [.., +6): W^T LDS transpose (one per layer,matrix); m==0 also biasSum
#define NB_INIT  (NTOT * EMBC / 4 / 256)   // 6250
#define NB_SCAT  ((NNZC + 4095) / 4096)    // 782
__global__ __launch_bounds__(256) void k_prepscat(
    const intx4* __restrict__ row4, const intx4* __restrict__ col4,
    const floatx4* __restrict__ val4, int* __restrict__ gbcur, u64* __restrict__ eb,
    const float4* __restrict__ ue, const float4* __restrict__ ie, ushort4* __restrict__ xb0,
    const float* __restrict__ Wgc, const float* __restrict__ Wbi,
    const float* __restrict__ bgc, const float* __restrict__ bbi,
    unsigned short* __restrict__ wgT, unsigned short* __restrict__ wbT,
    float* __restrict__ biasSum) {
    __shared__ int bh[NBKT], bbase[NBKT], bcur[NBKT];
    __shared__ float wlds[64 * 65];
    int tid = threadIdx.x;
    if (blockIdx.x < NB_SCAT) {
        for (int i = tid; i < NBKT; i += 256) { bh[i] = 0; bcur[i] = 0; }
        __syncthreads();
        long gbase = (long)blockIdx.x * 1024;     // 1024 groups = 4096 edges per block
        u64 e[16]; int bk[16];
        #pragma unroll
        for (int it = 0; it < 4; ++it) {
            long g = gbase + it * 256 + tid;
            if (g < NGRP) {
                intx4 r = __builtin_nontemporal_load(row4 + g);
                intx4 c = __builtin_nontemporal_load(col4 + g);
                floatx4 v = __builtin_nontemporal_load(val4 + g);
                e[it*4+0] = ((u64)r.x << 32) | ((u64)(unsigned)c.x << 15) | v2fix(v.x); bk[it*4+0] = r.x >> 9;
                e[it*4+1] = ((u64)r.y << 32) | ((u64)(unsigned)c.y << 15) | v2fix(v.y); bk[it*4+1] = r.y >> 9;
                e[it*4+2] = ((u64)r.z << 32) | ((u64)(unsigned)c.z << 15) | v2fix(v.z); bk[it*4+2] = r.z >> 9;
                e[it*4+3] = ((u64)r.w << 32) | ((u64)(unsigned)c.w << 15) | v2fix(v.w); bk[it*4+3] = r.w >> 9;
                atomicAdd(&bh[bk[it*4+0]], 1);
                atomicAdd(&bh[bk[it*4+1]], 1);
                atomicAdd(&bh[bk[it*4+2]], 1);
                atomicAdd(&bh[bk[it*4+3]], 1);
            } else {
                bk[it*4+0] = bk[it*4+1] = bk[it*4+2] = bk[it*4+3] = -1;
            }
        }
        __syncthreads();
        for (int i = tid; i < NBKT; i += 256)
            if (bh[i] > 0) bbase[i] = atomicAdd(&gbcur[i], bh[i]);   // RELATIVE base
        __syncthreads();
        #pragma unroll
        for (int i = 0; i < 16; i++) {
            if (bk[i] >= 0) {
                int p = bk[i] * CAP + bbase[bk[i]] + atomicAdd(&bcur[bk[i]], 1);
                eb[p] = e[i];
            }
        }
    } else if (blockIdx.x < NB_SCAT + NB_INIT) {
        long i = (long)(blockIdx.x - NB_SCAT) * 256 + tid;
        const long nu4 = (long)N_USERC * EMBC / 4;
        float4 v = (i < nu4) ? ue[i] : ie[i - nu4];
        ushort4 b; b.x = f2bf(v.x); b.y = f2bf(v.y); b.z = f2bf(v.z); b.w = f2bf(v.w);
        xb0[i] = b;
    } else {
        int wb = blockIdx.x - NB_SCAT - NB_INIT;
        int k = wb >> 1, m = wb & 1;
        const float* W = (m ? Wbi : Wgc) + k * 4096;
        unsigned short* WT = (m ? wbT : wgT) + k * 4096;
        #pragma unroll
        for (int it = 0; it < 4; ++it) {
            int i = it * 1024 + tid * 4;          // linear index d*64+c, float4
            float4 v = *(const float4*)(W + i);
            int d = i >> 6, c = i & 63;
            wlds[d * 65 + c + 0] = v.x;
            wlds[d * 65 + c + 1] = v.y;
            wlds[d * 65 + c + 2] = v.z;
            wlds[d * 65 + c + 3] = v.w;
        }
        __syncthreads();
        int c = tid >> 2;
        int d0 = (tid & 3) * 16;
        unsigned short vals[16];
        #pragma unroll
        for (int j = 0; j < 16; ++j)
            vals[j] = f2bf(wlds[(d0 + j) * 65 + c]);
        *(uint4*)(WT + tid * 16)     = *(const uint4*)(vals);
        *(uint4*)(WT + tid * 16 + 8) = *(const uint4*)(vals + 8);
        if (m == 0 && tid < 64) biasSum[k * 64 + tid] = bgc[k * 64 + tid] + bbi[k * 64 + tid];
    }
}

// ---------------- bucket -> row-CSR (rp2 = start,end) : 1024 threads/block, fixed bases ----------------
__global__ __launch_bounds__(1024) void k_csrC(const u64* __restrict__ eb, const int* __restrict__ gbcur,
                                               intx2* __restrict__ rp2, unsigned* __restrict__ ecv) {
    __shared__ int lhist[512];
    __shared__ int lcur[512];
    __shared__ int sm[256];
    int b = blockIdx.x;
    int tid = threadIdx.x;
    int row0 = b << 9;
    if (tid < 512) lhist[tid] = 0;
    __syncthreads();
    int start = b * CAP;
    int end = start + gbcur[b];          // relative cursor after scatter
    for (int e = start + tid; e < end; e += 1024) {
        u64 w = eb[e];
        int rl = (int)((w >> 32) & 0x1FFFF) - row0;
        atomicAdd(&lhist[rl], 1);
    }
    __syncthreads();
    int h0 = 0, h1 = 0, pair = 0;
    if (tid < 256) {
        h0 = lhist[2 * tid]; h1 = lhist[2 * tid + 1];
        pair = h0 + h1;
        sm[tid] = pair;
    }
    __syncthreads();
    for (int off = 1; off < 256; off <<= 1) {
        int u = 0;
        if (tid < 256 && tid >= off) u = sm[tid - off];
        __syncthreads();
        if (tid < 256) sm[tid] += u;
        __syncthreads();
    }
    if (tid < 256) {
        int pairExcl = sm[tid] - pair;
        int e0 = start + pairExcl;
        int e1 = e0 + h0;
        lcur[2 * tid] = e0;
        lcur[2 * tid + 1] = e1;
        int rg0 = row0 + 2 * tid, rg1 = rg0 + 1;
        if (rg0 < NTOT) { intx2 v; v.x = e0; v.y = e1; rp2[rg0] = v; }
        if (rg1 < NTOT) { intx2 v; v.x = e1; v.y = e1 + h1; rp2[rg1] = v; }
    }
    __syncthreads();
    for (int e = start + tid; e < end; e += 1024) {
        u64 w = eb[e];
        int rl = (int)((w >> 32) & 0x1FFFF) - row0;
        int p = atomicAdd(&lcur[rl], 1);
        ecv[p] = (unsigned)(w & 0xFFFFFFFFu);   // col<<15 | val15
    }
}

// ---------------- SpMM: round-7 proven body (persistent grid-stride, wave-per-row) ----------------
#define SPMM_BLOCKS 2048
__global__ __launch_bounds__(256) void k_spmm(const intx2* __restrict__ rp2, const unsigned* __restrict__ ecv,
                                              const unsigned short* __restrict__ xb,
                                              unsigned short* __restrict__ side_bf) {
    int wid = blockIdx.x * 4 + (threadIdx.x >> 6);
    int lane = threadIdx.x & 63;
    int q = lane >> 4;
    int t4 = (lane & 15) * 4;
    unsigned tb = (unsigned)(t4 * 2);          // byte offset of this lane's 4-elem chunk
    const char* xbc = (const char*)xb;
    for (int r = wid; r < NTOT; r += SPMM_BLOCKS * 4) {
        intx2 se = rp2[r];
        int s = se.x;
        int len = se.y - s;
        const unsigned* ebase = ecv + s;
        floatx2 acc01 = {0.f, 0.f}, acc23 = {0.f, 0.f};

        int nfull = len >> 4;
        int j = 0;
        for (int it = 0; it < nfull; ++it, j += 16) {
            unsigned pk[4];
            #pragma unroll
            for (int u = 0; u < 4; ++u)
                pk[u] = __builtin_nontemporal_load(ebase + j + u * 4 + q);
            uintx2 xv[4];
            #pragma unroll
            for (int u = 0; u < 4; ++u)
                xv[u] = *(const uintx2*)(xbc + ((pk[u] >> 15) * 128u + tb));
            #pragma unroll
            for (int u = 0; u < 4; ++u) {
                float w = (float)(pk[u] & 0x7fffu);
                floatx2 x01, x23;
                x01.x = __uint_as_float(xv[u].x << 16);
                x01.y = __uint_as_float(xv[u].x & 0xffff0000u);
                x23.x = __uint_as_float(xv[u].y << 16);
                x23.y = __uint_as_float(xv[u].y & 0xffff0000u);
                acc01 += w * x01;
                acc23 += w * x23;
            }
        }
        if (j < len) {
            unsigned pk[4]; bool vm[4];
            #pragma unroll
            for (int u = 0; u < 4; ++u) {
                int je = j + u * 4 + q;
                vm[u] = (je < len);
                pk[u] = __builtin_nontemporal_load(ebase + (vm[u] ? je : 0));
            }
            uintx2 xv[4];
            #pragma unroll
            for (int u = 0; u < 4; ++u)
                xv[u] = *(const uintx2*)(xbc + ((pk[u] >> 15) * 128u + tb));
            #pragma unroll
            for (int u = 0; u < 4; ++u) {
                float w = vm[u] ? (float)(pk[u] & 0x7fffu) : 0.f;
                floatx2 x01, x23;
                x01.x = __uint_as_float(xv[u].x << 16);
                x01.y = __uint_as_float(xv[u].x & 0xffff0000u);
                x23.x = __uint_as_float(xv[u].y << 16);
                x23.y = __uint_as_float(xv[u].y & 0xffff0000u);
                acc01 += w * x01;
                acc23 += w * x23;
            }
        }

        float a0 = acc01.x, a1 = acc01.y, a2 = acc23.x, a3 = acc23.y;
        a0 += __shfl_xor(a0, 16); a1 += __shfl_xor(a1, 16); a2 += __shfl_xor(a2, 16); a3 += __shfl_xor(a3, 16);
        a0 += __shfl_xor(a0, 32); a1 += __shfl_xor(a1, 32); a2 += __shfl_xor(a2, 32); a3 += __shfl_xor(a3, 32);
        if (lane < 16) {
            const float SC = 1.0f / 1048576.0f;    // deferred fixed-point scale (exact pow2)
            ushort4 o; o.x = f2bf(a0 * SC); o.y = f2bf(a1 * SC); o.z = f2bf(a2 * SC); o.w = f2bf(a3 * SC);
            *(ushort4*)(side_bf + (long)r * EMBC + t4) = o;
        }
    }
}

// ------------- MFMA layer: xb_in -> xb_out -------------
#define RPB 128
#define LDP 72
__global__ __launch_bounds__(256) void k_layer_mfma(
    const unsigned short* __restrict__ side_bf, const unsigned short* __restrict__ xb_in,
    unsigned short* __restrict__ xb_out,
    const unsigned short* __restrict__ wgT, const unsigned short* __restrict__ wbT,
    const float* __restrict__ biasSum)
{
    __shared__ unsigned short sS[RPB * LDP];
    __shared__ unsigned short sM[RPB * LDP];
    __shared__ unsigned short sWg[64 * LDP];
    __shared__ unsigned short sWb[64 * LDP];
    __shared__ float sBias[64];

    int tid = threadIdx.x;
    int row0 = blockIdx.x * RPB;

    #pragma unroll
    for (int it = 0; it < 2; ++it) {
        int item = it * 256 + tid;          // 0..511
        int c = item >> 3, ch = item & 7;
        *(uint4*)(sWg + c * LDP + ch * 8) = *(const uint4*)(wgT + c * 64 + ch * 8);
        *(uint4*)(sWb + c * LDP + ch * 8) = *(const uint4*)(wbT + c * 64 + ch * 8);
    }
    if (tid < 64) sBias[tid] = biasSum[tid];

    #pragma unroll
    for (int it = 0; it < (RPB * 8) / 256; ++it) {
        int item = it * 256 + tid;
        int r = item >> 3, ch = item & 7;
        long grow = row0 + r;
        uint4 sv = make_uint4(0, 0, 0, 0), ev = make_uint4(0, 0, 0, 0);
        if (grow < NTOT) {
            sv = *(const uint4*)(side_bf + grow * 64 + ch * 8);
            ev = *(const uint4*)(xb_in + grow * 64 + ch * 8);
        }
        uint4 mv;
        mv.x = f2bf(bf2f(ev.x & 0xffff) * bf2f(sv.x & 0xffff)) |
               ((unsigned int)f2bf(bf2f(ev.x >> 16) * bf2f(sv.x >> 16)) << 16);
        mv.y = f2bf(bf2f(ev.y & 0xffff) * bf2f(sv.y & 0xffff)) |
               ((unsigned int)f2bf(bf2f(ev.y >> 16) * bf2f(sv.y >> 16)) << 16);
        mv.z = f2bf(bf2f(ev.z & 0xffff) * bf2f(sv.z & 0xffff)) |
               ((unsigned int)f2bf(bf2f(ev.z >> 16) * bf2f(sv.z >> 16)) << 16);
        mv.w = f2bf(bf2f(ev.w & 0xffff) * bf2f(sv.w & 0xffff)) |
               ((unsigned int)f2bf(bf2f(ev.w >> 16) * bf2f(sv.w >> 16)) << 16);
        *(uint4*)(sS + r * LDP + ch * 8) = sv;
        *(uint4*)(sM + r * LDP + ch * 8) = mv;
    }
    __syncthreads();

    int wave = tid >> 6, lane = tid & 63;
    int quad = lane >> 4, l16 = lane & 15;

    floatx4 accG[2][4], accB[2][4];
    #pragma unroll
    for (int rt = 0; rt < 2; rt++)
        #pragma unroll
        for (int ct = 0; ct < 4; ct++) {
            accG[rt][ct] = (floatx4){0.f, 0.f, 0.f, 0.f};
            accB[rt][ct] = (floatx4){0.f, 0.f, 0.f, 0.f};
        }

    #pragma unroll
    for (int kc = 0; kc < 64; kc += 32) {
        shortx8 aS[2], aM[2];
        #pragma unroll
        for (int rt = 0; rt < 2; rt++) {
            int r = wave * 32 + rt * 16 + l16;
            aS[rt] = *(const shortx8*)(sS + r * LDP + kc + quad * 8);
            aM[rt] = *(const shortx8*)(sM + r * LDP + kc + quad * 8);
        }
        #pragma unroll
        for (int ct = 0; ct < 4; ct++) {
            int c = ct * 16 + l16;
            shortx8 bG = *(const shortx8*)(sWg + c * LDP + kc + quad * 8);
            shortx8 bB = *(const shortx8*)(sWb + c * LDP + kc + quad * 8);
            #pragma unroll
            for (int rt = 0; rt < 2; rt++) {
                accG[rt][ct] = __builtin_amdgcn_mfma_f32_16x16x32_bf16(aS[rt], bG, accG[rt][ct], 0, 0, 0);
                accB[rt][ct] = __builtin_amdgcn_mfma_f32_16x16x32_bf16(aM[rt], bB, accB[rt][ct], 0, 0, 0);
            }
        }
    }

    #pragma unroll
    for (int rt = 0; rt < 2; rt++)
        #pragma unroll
        for (int ct = 0; ct < 4; ct++) {
            int c = ct * 16 + l16;
            float bs = sBias[c];
            #pragma unroll
            for (int reg = 0; reg < 4; reg++) {
                int r = wave * 32 + rt * 16 + quad * 4 + reg;
                long grow = row0 + r;
                if (grow < NTOT) {
                    float v = accG[rt][ct][reg] + accB[rt][ct][reg] + bs;
                    float o = (v > 0.f) ? v : 0.2f * v;
                    xb_out[grow * 64 + c] = f2bf(o);
                }
            }
        }
}

// ------------- single fused gather: all 4 column-blocks (layer 0 raw, 1-3 normalized) -------------
__global__ __launch_bounds__(256) void k_gatherAll(
    const unsigned short* __restrict__ xb0, const unsigned short* __restrict__ xb1,
    const unsigned short* __restrict__ xb2, const unsigned short* __restrict__ xb3,
    const int* __restrict__ users, const int* __restrict__ pos, const int* __restrict__ neg,
    float* __restrict__ out) {
    int gw = (blockIdx.x * blockDim.x + threadIdx.x) >> 6;   // slot*4 + layer
    int lane = threadIdx.x & 63;
    int slot = gw >> 2, layer = gw & 3;
    if (slot >= NSLOT) return;
    int row;
    if (slot < BATCHC)          row = users[slot];
    else if (slot < 2 * BATCHC) row = N_USERC + pos[slot - BATCHC];
    else                        row = N_USERC + neg[slot - 2 * BATCHC];
    const unsigned short* src = (layer == 0) ? xb0 : (layer == 1) ? xb1 : (layer == 2) ? xb2 : xb3;
    float v = bf2f(src[(long)row * 64 + lane]);
    if (layer != 0) {
        float ss = v * v;
        for (int off = 32; off > 0; off >>= 1) ss += __shfl_xor(ss, off);
        float nrm = fmaxf(sqrtf(ss), 1e-12f);
        v = v / nrm;
    }
    out[(long)slot * 256 + layer * 64 + lane] = v;
}

extern "C" void kernel_launch(void* const* d_in, const int* in_sizes, int n_in,
                              void* d_out, int out_size, void* d_ws, size_t ws_size,
                              hipStream_t stream) {
    const int*   users   = (const int*)d_in[0];
    const int*   pos     = (const int*)d_in[1];
    const int*   neg     = (const int*)d_in[2];
    const int*   adj_row = (const int*)d_in[3];
    const int*   adj_col = (const int*)d_in[4];
    const float* adj_val = (const float*)d_in[5];
    const float* user_emb = (const float*)d_in[6];
    const float* item_emb = (const float*)d_in[7];
    const float* W_gc = (const float*)d_in[8];
    const float* b_gc = (const float*)d_in[9];
    const float* W_bi = (const float*)d_in[10];
    const float* b_bi = (const float*)d_in[11];
    float* out = (float*)d_out;

    // workspace (~82 MB). Aliasing: xb2/xb3 overlay eb (eb dead after csrC).
    char* p = (char*)d_ws;
    unsigned* ecv = (unsigned*)p;               p += (size_t)NBKT * CAP * 4;   // 13.65 MB (gapped CSR edges)
    u64*  eb  = (u64*)p;                        p += (size_t)NBKT * CAP * 8;   // 27.3 MB
    unsigned short* xb2 = (unsigned short*)eb;
    unsigned short* xb3 = (unsigned short*)((char*)eb + (size_t)NTOT * EMBC * 2);
    unsigned short* side_bf = (unsigned short*)p; p += (size_t)NTOT * EMBC * 2;
    unsigned short* xb0 = (unsigned short*)p;   p += (size_t)NTOT * EMBC * 2;
    unsigned short* xb1 = (unsigned short*)p;   p += (size_t)NTOT * EMBC * 2;
    intx2* rp2 = (intx2*)p;                     p += (size_t)NTOT * 8;
    int*  gbcur = (int*)p;                      p += 1024;
    unsigned short* wgT = (unsigned short*)p;   p += 3 * 4096 * 2;
    unsigned short* wbT = (unsigned short*)p;   p += 3 * 4096 * 2;
    float* biasSum = (float*)p;                 p += 3 * 64 * 4;

    hipMemsetAsync(gbcur, 0, 1024, stream);    // relative bucket cursors start at 0

    k_prepscat<<<NB_SCAT + NB_INIT + 6, 256, 0, stream>>>(
        (const intx4*)adj_row, (const intx4*)adj_col, (const floatx4*)adj_val, gbcur, eb,
        (const float4*)user_emb, (const float4*)item_emb, (ushort4*)xb0,
        W_gc, W_bi, b_gc, b_bi, wgT, wbT, biasSum);

    k_csrC<<<NBKT, 1024, 0, stream>>>(eb, gbcur, rp2, ecv);

    unsigned short* xbs[4] = {xb0, xb1, xb2, xb3};
    const int NB_LAYER = (NTOT + RPB - 1) / RPB;
    for (int k = 0; k < 3; k++) {
        k_spmm<<<SPMM_BLOCKS, 256, 0, stream>>>(rp2, ecv, xbs[k], side_bf);
        k_layer_mfma<<<NB_LAYER, 256, 0, stream>>>(side_bf, xbs[k], xbs[k + 1],
            wgT + (size_t)k * 4096, wbT + (size_t)k * 4096, biasSum + (size_t)k * 64);
    }
    k_gatherAll<<<(NSLOT * 4) / 4, 256, 0, stream>>>(xb0, xb1, xb2, xb3, users, pos, neg, out);
}